// Round 3
// baseline (1277.253 us; speedup 1.0000x reference)
//
#include <hip/hip_runtime.h>
#include <cstdint>

// Two-phase SNN:
//   Phase A (snn_gemm): cur1[b,t,h] = x[b,t,:] @ W1[h,:] + b1[h]  — feedforward,
//     massively parallel over B*T rows. W1 row in VGPRs; x rows read via
//     WAVE-UNIFORM loads (-> s_load -> SGPR operand bus, no replication cost).
//     R2 analysis: LDS broadcast of x cost ~1536 CU-cycles/step (replicated
//     1 KB register delivery per b128 broadcast) — SGPR delivery is free.
//   Phase B (snn_rec): sequential recurrence, 1 wave per batch element.
//     Layer 2 = dense predicated FMA over VGPR-resident W2 row (bit-exact:
//     fmaf(0,w,c)=c exactly, fmaf(1,w,c)=c+w rounded once, ascending j ==
//     R2's sparse order). Layer 3 sparse via tiny LDS (s2 almost always 0).
//     cur1 prefetched 8 steps ahead in registers (coalesced, non-replicated).
// Fallback: if ws_size can't hold cur1 (134 MB), launch the proven R2 fused
// kernel (deterministic host-side branch; graph-capture safe).

#define TT  512
#define DIN 128
#define HH  64
#define OO  20

// ---------------------------------------------------------------- Phase A
__global__ __launch_bounds__(64, 1) void snn_gemm(
    const float* __restrict__ x,      // (B*T, 128)
    const float* __restrict__ W1,     // (64, 128)
    const float* __restrict__ b1,     // (64,)
    float* __restrict__ cur1,         // (B*T, 64)
    int nrows)
{
    const int lane = threadIdx.x;

    float w1[DIN];
#pragma unroll
    for (int k = 0; k < DIN; k += 4) {
        const float4 v = *reinterpret_cast<const float4*>(W1 + lane * DIN + k);
        w1[k + 0] = v.x; w1[k + 1] = v.y; w1[k + 2] = v.z; w1[k + 3] = v.w;
    }
    const float bb1 = b1[lane];

    const int nchunks = nrows >> 2;               // 4 rows per chunk
    for (int c = blockIdx.x; c < nchunks; c += gridDim.x) {
        const int row0 = c << 2;
        const float* xr = x + (size_t)row0 * DIN; // wave-uniform base

        float a[4][4];
#pragma unroll
        for (int r = 0; r < 4; ++r) { a[r][0] = a[r][1] = a[r][2] = a[r][3] = 0.0f; }

#pragma unroll
        for (int k = 0; k < DIN; k += 4) {
#pragma unroll
            for (int r = 0; r < 4; ++r) {
                // uniform address -> s_load_dwordx4; value consumed as SGPR
                // operand of v_fmac (1 SGPR read per VALU op allowed).
                const float4 xk = *reinterpret_cast<const float4*>(xr + r * DIN + k);
                a[r][0] = fmaf(xk.x, w1[k + 0], a[r][0]);
                a[r][1] = fmaf(xk.y, w1[k + 1], a[r][1]);
                a[r][2] = fmaf(xk.z, w1[k + 2], a[r][2]);
                a[r][3] = fmaf(xk.w, w1[k + 3], a[r][3]);
            }
        }
        // Summation structure identical to R2 (bit-exact requirement):
        // ((a0+a1)+(a2+a3)) + b1
#pragma unroll
        for (int r = 0; r < 4; ++r) {
            const float d = __fadd_rn(
                __fadd_rn(__fadd_rn(a[r][0], a[r][1]), __fadd_rn(a[r][2], a[r][3])),
                bb1);
            cur1[(size_t)(row0 + r) * HH + lane] = d;   // coalesced 256 B/row
        }
    }
}

// ---------------------------------------------------------------- Phase B
__global__ __launch_bounds__(64, 1) void snn_rec(
    const float* __restrict__ cur1,   // (B*T, 64)
    const float* __restrict__ beta1,
    const float* __restrict__ W2,     // (64, 64)
    const float* __restrict__ b2,
    const float* __restrict__ beta2,
    const float* __restrict__ W3,     // (20, 64)
    const float* __restrict__ b3,
    const float* __restrict__ beta3,
    float* __restrict__ out)          // (B, T, 20)
{
    __shared__ float sW3T[HH * 21];   // sW3T[j*21+o] = W3[o][j]; stride 21 conflict-free

    const int lane = threadIdx.x;
    const int b    = blockIdx.x;

    // W2 row `lane` resident in VGPRs (one-time load)
    float w2r[HH];
#pragma unroll
    for (int j = 0; j < HH; j += 4) {
        const float4 v = *reinterpret_cast<const float4*>(W2 + lane * HH + j);
        w2r[j + 0] = v.x; w2r[j + 1] = v.y; w2r[j + 2] = v.z; w2r[j + 3] = v.w;
    }
    for (int oo = 0; oo < OO; ++oo) {
        sW3T[lane * 21 + oo] = W3[oo * HH + lane];
    }

    const float bt1 = fminf(fmaxf(beta1[lane], 0.0f), 1.0f);
    const float bb2 = b2[lane];
    const float bt2 = fminf(fmaxf(beta2[lane], 0.0f), 1.0f);
    const int   o   = (lane < OO) ? lane : 0;
    const float bb3 = b3[o];
    const float bt3 = fminf(fmaxf(beta3[o], 0.0f), 1.0f);
    float m1 = 0.0f, m2 = 0.0f, m3 = 0.0f;

    const float* cb   = cur1 + (size_t)b * TT * HH + lane;
    float*       outb = out  + (size_t)b * TT * OO;
    const float* sW3row = sW3T + o;

    // 8-step register prefetch ring for cur1 (coalesced dword per lane per step)
    float pc[8];
#pragma unroll
    for (int u = 0; u < 8; ++u) pc[u] = cb[(size_t)u * HH];

    for (int t8 = 0; t8 < TT; t8 += 8) {
#pragma unroll
        for (int u = 0; u < 8; ++u) {
            const int t = t8 + u;
            const float cur1v = pc[u];
            const int tn = (t + 8 < TT) ? (t + 8) : (TT - 1);   // clamped (value unused at tail)
            pc[u] = cb[(size_t)tn * HH];

            // layer 1 membrane (phase-A cur1 is bit-identical to fused version)
            const float r1 = (m1 > 1.0f) ? 1.0f : 0.0f;
            m1 = __fsub_rn(__fadd_rn(__fmul_rn(bt1, m1), cur1v), r1);
            const unsigned long long s1 = __ballot(m1 > 1.0f);

            // layer 2: dense predicated FMA, ascending j (== sparse order with
            // exact +0.0 no-ops interleaved)
            float c2 = bb2;
#pragma unroll
            for (int j = 0; j < HH; ++j) {
                const float f = (s1 & (1ull << j)) ? 1.0f : 0.0f;  // wave-uniform scalar
                c2 = fmaf(f, w2r[j], c2);
            }
            const float r2 = (m2 > 1.0f) ? 1.0f : 0.0f;
            m2 = __fsub_rn(__fadd_rn(__fmul_rn(bt2, m2), c2), r2);
            const unsigned long long s2 = __ballot(m2 > 1.0f);

            // layer 3: s2 ~ always 0 -> fast skip; sparse LDS path otherwise
            float c3 = bb3;
            if (s2) {
                unsigned long long mm = s2;
                int j = __builtin_ctzll(mm); mm &= (mm - 1);
                float v = sW3row[j * 21];
                while (mm) {
                    const int j2 = __builtin_ctzll(mm); mm &= (mm - 1);
                    const float v2 = sW3row[j2 * 21];
                    c3 = __fadd_rn(c3, v);
                    v = v2;
                }
                c3 = __fadd_rn(c3, v);
            }
            m3 = __fadd_rn(__fmul_rn(bt3, m3), c3);
            if (lane < OO) outb[t * OO + lane] = m3;
        }
    }
}

// ------------------------------------------------- Fallback: R2 fused kernel
__global__ __launch_bounds__(64, 1) void snn_fused(
    const float* __restrict__ x, const float* __restrict__ W1,
    const float* __restrict__ b1, const float* __restrict__ beta1,
    const float* __restrict__ W2, const float* __restrict__ b2,
    const float* __restrict__ beta2, const float* __restrict__ W3,
    const float* __restrict__ b3, const float* __restrict__ beta3,
    float* __restrict__ out)
{
    __shared__ float sW2T[HH * 65];
    __shared__ float sW3T[HH * 21];
    __shared__ float sx[8 * DIN];

    const int lane = threadIdx.x;
    const int b    = blockIdx.x;

    float w1[DIN];
#pragma unroll
    for (int k = 0; k < DIN; k += 4) {
        const float4 v = *reinterpret_cast<const float4*>(W1 + lane * DIN + k);
        w1[k + 0] = v.x; w1[k + 1] = v.y; w1[k + 2] = v.z; w1[k + 3] = v.w;
    }
    for (int h = 0; h < HH; ++h) sW2T[lane * 65 + h] = W2[h * HH + lane];
    for (int oo = 0; oo < OO; ++oo) sW3T[lane * 21 + oo] = W3[oo * HH + lane];

    const float bb1 = b1[lane];
    const float bt1 = fminf(fmaxf(beta1[lane], 0.0f), 1.0f);
    const float bb2 = b2[lane];
    const float bt2 = fminf(fmaxf(beta2[lane], 0.0f), 1.0f);
    const int   o   = (lane < OO) ? lane : 0;
    const float bb3 = b3[o];
    const float bt3 = fminf(fmaxf(beta3[o], 0.0f), 1.0f);
    float m1 = 0.0f, m2 = 0.0f, m3 = 0.0f;

    const float* xb   = x   + (size_t)b * TT * DIN;
    float*       outb = out + (size_t)b * TT * OO;
    const float* sW2row = sW2T + lane;
    const float* sW3row = sW3T + o;

    const float4 v0 = *reinterpret_cast<const float4*>(xb + 0 * DIN + 4 * lane);
    const float4 v1 = *reinterpret_cast<const float4*>(xb + 2 * DIN + 4 * lane);
    float4 pr = *reinterpret_cast<const float4*>(xb + 4 * DIN + 4 * lane);
    float4 pf = *reinterpret_cast<const float4*>(xb + 6 * DIN + 4 * lane);
    *reinterpret_cast<float4*>(sx + 0 * DIN + 4 * lane) = v0;
    *reinterpret_cast<float4*>(sx + 2 * DIN + 4 * lane) = v1;

    for (int t = 0; t < TT; ++t) {
        const float* xr = sx + (t & 7) * DIN;
        float a0 = 0.0f, a1 = 0.0f, a2 = 0.0f, a3 = 0.0f;
#pragma unroll
        for (int k = 0; k < DIN; k += 4) {
            const float4 xk = *reinterpret_cast<const float4*>(xr + k);
            a0 = fmaf(xk.x, w1[k + 0], a0);
            a1 = fmaf(xk.y, w1[k + 1], a1);
            a2 = fmaf(xk.z, w1[k + 2], a2);
            a3 = fmaf(xk.w, w1[k + 3], a3);
        }
        const float cur1 = __fadd_rn(__fadd_rn(__fadd_rn(a0, a1), __fadd_rn(a2, a3)), bb1);
        const float r1 = (m1 > 1.0f) ? 1.0f : 0.0f;
        m1 = __fsub_rn(__fadd_rn(__fmul_rn(bt1, m1), cur1), r1);
        const unsigned long long s1 = __ballot(m1 > 1.0f);

        float c2 = bb2;
        {
            unsigned long long mm = s1;
            if (mm) {
                int j = __builtin_ctzll(mm); mm &= (mm - 1);
                float v = sW2row[j * 65];
                while (mm) {
                    const int j2 = __builtin_ctzll(mm); mm &= (mm - 1);
                    const float v2 = sW2row[j2 * 65];
                    c2 = __fadd_rn(c2, v);
                    v = v2;
                }
                c2 = __fadd_rn(c2, v);
            }
        }
        const float r2 = (m2 > 1.0f) ? 1.0f : 0.0f;
        m2 = __fsub_rn(__fadd_rn(__fmul_rn(bt2, m2), c2), r2);
        const unsigned long long s2 = __ballot(m2 > 1.0f);

        float c3 = bb3;
        if (s2) {
            unsigned long long mm = s2;
            int j = __builtin_ctzll(mm); mm &= (mm - 1);
            float v = sW3row[j * 21];
            while (mm) {
                const int j2 = __builtin_ctzll(mm); mm &= (mm - 1);
                const float v2 = sW3row[j2 * 21];
                c3 = __fadd_rn(c3, v);
                v = v2;
            }
            c3 = __fadd_rn(c3, v);
        }
        m3 = __fadd_rn(__fmul_rn(bt3, m3), c3);
        if (lane < OO) outb[t * OO + lane] = m3;

        if (((t & 1) == 0) && (t + 4 < TT)) {
            *reinterpret_cast<float4*>(sx + ((t + 4) & 7) * DIN + 4 * lane) = pr;
            pr = pf;
            if (t + 8 < TT) {
                pf = *reinterpret_cast<const float4*>(xb + (t + 8) * DIN + 4 * lane);
            }
        }
    }
}

extern "C" void kernel_launch(void* const* d_in, const int* in_sizes, int n_in,
                              void* d_out, int out_size, void* d_ws, size_t ws_size,
                              hipStream_t stream) {
    const float* x     = (const float*)d_in[0];
    const float* W1    = (const float*)d_in[1];
    const float* b1    = (const float*)d_in[2];
    const float* beta1 = (const float*)d_in[3];
    const float* W2    = (const float*)d_in[4];
    const float* b2    = (const float*)d_in[5];
    const float* beta2 = (const float*)d_in[6];
    const float* W3    = (const float*)d_in[7];
    const float* b3    = (const float*)d_in[8];
    const float* beta3 = (const float*)d_in[9];

    const int B     = in_sizes[0] / (TT * DIN);   // 1024
    const int nrows = B * TT;
    const size_t need = (size_t)nrows * HH * sizeof(float);   // 134 MB

    if (ws_size >= need) {
        float* cur1 = (float*)d_ws;
        snn_gemm<<<dim3(4096), dim3(64), 0, stream>>>(x, W1, b1, cur1, nrows);
        snn_rec<<<dim3(B), dim3(64), 0, stream>>>(
            cur1, beta1, W2, b2, beta2, W3, b3, beta3, (float*)d_out);
    } else {
        snn_fused<<<dim3(B), dim3(64), 0, stream>>>(
            x, W1, b1, beta1, W2, b2, beta2, W3, b3, beta3, (float*)d_out);
    }
}

// Round 4
// 805.279 us; speedup vs baseline: 1.5861x; 1.5861x over previous
//
#include <hip/hip_runtime.h>
#include <cstdint>

// Fused SNN recurrence, R4: identical structure/arithmetic to R2 (bit-exact,
// absmax 0.0), with ONE fix: W1 row held in 32 NAMED float4 registers instead
// of a float[128] array. R1-R3 counters proved the arrays never reached VGPRs
// (VGPR_Count 116 with a 128-float array; 52 with a 64-float array): SROA runs
// before unrolling, dynamic indices keep the alloca alive, promote-alloca
// punts, and every step re-read 32 KB/wave of spilled weights from scratch
// (~16.8 GB of L2 traffic = the entire 546 us). Named variables cannot spill
// this way.

#define TT  512
#define DIN 128
#define HH  64
#define OO  20

__global__ __launch_bounds__(64, 1) void snn_fused(
    const float* __restrict__ x,      // (B, T, 128)
    const float* __restrict__ W1,     // (64, 128)
    const float* __restrict__ b1,
    const float* __restrict__ beta1,
    const float* __restrict__ W2,     // (64, 64)
    const float* __restrict__ b2,
    const float* __restrict__ beta2,
    const float* __restrict__ W3,     // (20, 64)
    const float* __restrict__ b3,
    const float* __restrict__ beta3,
    float* __restrict__ out)          // (B, T, 20)
{
    __shared__ float sW2T[HH * 65];   // sW2T[j*65+h] = W2[h][j]; stride 65 conflict-free
    __shared__ float sW3T[HH * 21];   // sW3T[j*21+o] = W3[o][j]; stride 21 conflict-free
    __shared__ float sx[8 * DIN];     // ring buffer: 8 timesteps of x

    const int lane = threadIdx.x;     // 0..63
    const int b    = blockIdx.x;      // batch element

    // ---- W1 row `lane` in 32 NAMED float4 registers (no array, no alloca)
    const float* w1p = W1 + lane * DIN;
#define W1LD(i) const float4 w##i = *reinterpret_cast<const float4*>(w1p + 4 * i);
    W1LD(0)  W1LD(1)  W1LD(2)  W1LD(3)  W1LD(4)  W1LD(5)  W1LD(6)  W1LD(7)
    W1LD(8)  W1LD(9)  W1LD(10) W1LD(11) W1LD(12) W1LD(13) W1LD(14) W1LD(15)
    W1LD(16) W1LD(17) W1LD(18) W1LD(19) W1LD(20) W1LD(21) W1LD(22) W1LD(23)
    W1LD(24) W1LD(25) W1LD(26) W1LD(27) W1LD(28) W1LD(29) W1LD(30) W1LD(31)
#undef W1LD

    // ---- stage W2^T / W3^T into padded LDS (bank-clean; LDS, not scratch)
    for (int h = 0; h < HH; ++h)  sW2T[lane * 65 + h]  = W2[h * HH + lane];
    for (int oo = 0; oo < OO; ++oo) sW3T[lane * 21 + oo] = W3[oo * HH + lane];

    // ---- per-lane constants / state
    const float bb1 = b1[lane];
    const float bt1 = fminf(fmaxf(beta1[lane], 0.0f), 1.0f);
    const float bb2 = b2[lane];
    const float bt2 = fminf(fmaxf(beta2[lane], 0.0f), 1.0f);
    const int   o   = (lane < OO) ? lane : 0;
    const float bb3 = b3[o];
    const float bt3 = fminf(fmaxf(beta3[o], 0.0f), 1.0f);
    float m1 = 0.0f, m2 = 0.0f, m3 = 0.0f;

    const float* xb   = x   + (size_t)b * TT * DIN;
    float*       outb = out + (size_t)b * TT * OO;
    const float* sW2row = sW2T + lane;   // + j*65
    const float* sW3row = sW3T + o;      // + j*21

    // ---- x prefetch pipeline: rows 0..7 staged/in-flight (named float4 regs)
    const float4 v0 = *reinterpret_cast<const float4*>(xb + 0 * DIN + 4 * lane); // rows 0,1
    const float4 v1 = *reinterpret_cast<const float4*>(xb + 2 * DIN + 4 * lane); // rows 2,3
    float4 pr = *reinterpret_cast<const float4*>(xb + 4 * DIN + 4 * lane);       // rows 4,5
    float4 pf = *reinterpret_cast<const float4*>(xb + 6 * DIN + 4 * lane);       // rows 6,7
    *reinterpret_cast<float4*>(sx + 0 * DIN + 4 * lane) = v0;
    *reinterpret_cast<float4*>(sx + 2 * DIN + 4 * lane) = v1;
    // Single-wave block: no __syncthreads needed anywhere (proved R2).

    for (int t = 0; t < TT; ++t) {
        // ---- layer 1: cur1 = dot(x_t, W1[lane,:]) + b1[lane]
        // FMA order byte-identical to R1/R2 (matches numpy bit-for-bit):
        // a0 takes k=0,4,8,..., a1 k=1,5,9,..., etc.; combine ((a0+a1)+(a2+a3))+b1.
        const float* xr = sx + (t & 7) * DIN;
        float a0 = 0.0f, a1 = 0.0f, a2 = 0.0f, a3 = 0.0f;
#define MAC4(i) { const float4 xk = *reinterpret_cast<const float4*>(xr + 4 * i); \
                  a0 = fmaf(xk.x, w##i.x, a0); a1 = fmaf(xk.y, w##i.y, a1);       \
                  a2 = fmaf(xk.z, w##i.z, a2); a3 = fmaf(xk.w, w##i.w, a3); }
        MAC4(0)  MAC4(1)  MAC4(2)  MAC4(3)  MAC4(4)  MAC4(5)  MAC4(6)  MAC4(7)
        MAC4(8)  MAC4(9)  MAC4(10) MAC4(11) MAC4(12) MAC4(13) MAC4(14) MAC4(15)
        MAC4(16) MAC4(17) MAC4(18) MAC4(19) MAC4(20) MAC4(21) MAC4(22) MAC4(23)
        MAC4(24) MAC4(25) MAC4(26) MAC4(27) MAC4(28) MAC4(29) MAC4(30) MAC4(31)
#undef MAC4
        const float cur1 = __fadd_rn(__fadd_rn(__fadd_rn(a0, a1), __fadd_rn(a2, a3)), bb1);

        // reset uses PREVIOUS membrane; update path matches numpy op-for-op
        const float r1 = (m1 > 1.0f) ? 1.0f : 0.0f;
        m1 = __fsub_rn(__fadd_rn(__fmul_rn(bt1, m1), cur1), r1);
        const unsigned long long s1 = __ballot(m1 > 1.0f);

        // ---- layer 2: sparse accumulate, 2-stage pipelined (ascending j order)
        float c2 = bb2;
        {
            unsigned long long mm = s1;
            if (mm) {
                int j = __builtin_ctzll(mm); mm &= (mm - 1);
                float v = sW2row[j * 65];
                while (mm) {
                    const int j2 = __builtin_ctzll(mm); mm &= (mm - 1);
                    const float v2 = sW2row[j2 * 65];
                    c2 = __fadd_rn(c2, v);
                    v = v2;
                }
                c2 = __fadd_rn(c2, v);
            }
        }
        const float r2 = (m2 > 1.0f) ? 1.0f : 0.0f;
        m2 = __fsub_rn(__fadd_rn(__fmul_rn(bt2, m2), c2), r2);
        const unsigned long long s2 = __ballot(m2 > 1.0f);

        // ---- layer 3 (no reset); s2 almost always 0 -> fast skip
        float c3 = bb3;
        if (s2) {
            unsigned long long mm = s2;
            int j = __builtin_ctzll(mm); mm &= (mm - 1);
            float v = sW3row[j * 21];
            while (mm) {
                const int j2 = __builtin_ctzll(mm); mm &= (mm - 1);
                const float v2 = sW3row[j2 * 21];
                c3 = __fadd_rn(c3, v);
                v = v2;
            }
            c3 = __fadd_rn(c3, v);
        }
        m3 = __fadd_rn(__fmul_rn(bt3, m3), c3);
        if (lane < OO) outb[t * OO + lane] = m3;

        // ---- prefetch: even steps commit rows t+4,t+5 (loaded ~4 steps ago),
        // then issue load of rows t+8,t+9. All state in named float4 regs.
        if (((t & 1) == 0) && (t + 4 < TT)) {
            *reinterpret_cast<float4*>(sx + ((t + 4) & 7) * DIN + 4 * lane) = pr;
            pr = pf;
            if (t + 8 < TT) {
                pf = *reinterpret_cast<const float4*>(xb + (t + 8) * DIN + 4 * lane);
            }
        }
    }
}

extern "C" void kernel_launch(void* const* d_in, const int* in_sizes, int n_in,
                              void* d_out, int out_size, void* d_ws, size_t ws_size,
                              hipStream_t stream) {
    const float* x     = (const float*)d_in[0];
    const float* W1    = (const float*)d_in[1];
    const float* b1    = (const float*)d_in[2];
    const float* beta1 = (const float*)d_in[3];
    const float* W2    = (const float*)d_in[4];
    const float* b2    = (const float*)d_in[5];
    const float* beta2 = (const float*)d_in[6];
    const float* W3    = (const float*)d_in[7];
    const float* b3    = (const float*)d_in[8];
    const float* beta3 = (const float*)d_in[9];

    const int B = in_sizes[0] / (TT * DIN);   // 1024

    snn_fused<<<dim3(B), dim3(64), 0, stream>>>(
        x, W1, b1, beta1, W2, b2, beta2, W3, b3, beta3, (float*)d_out);
}